// Round 1
// baseline (188.908 us; speedup 1.0000x reference)
//
#include <hip/hip_runtime.h>
#include <cstdint>
#include <cmath>

#define NB 8192
#define ND 128

typedef __attribute__((ext_vector_type(8))) __bf16 bf16x8;
typedef __attribute__((ext_vector_type(2))) __bf16 bf16x2;
typedef __attribute__((ext_vector_type(4))) float f32x4;

// ---------------------------------------------------------------------------
// Kernel 1: row-normalize aug1/aug2 -> bf16, plus fp32 pos_sims (shared by
// both loss directions since dot(an1,an2) is symmetric).
// One wave per row: 64 lanes x float2 = 128 elements.
// ---------------------------------------------------------------------------
__global__ __launch_bounds__(256, 4) void knorm(const float* __restrict__ aug1,
                                                const float* __restrict__ aug2,
                                                __bf16* __restrict__ an,
                                                float* __restrict__ pos) {
  int wid = threadIdx.x >> 6;
  int l = threadIdx.x & 63;
  int row = blockIdx.x * 4 + wid;
  const float2* a1 = (const float2*)(aug1) + (size_t)row * 64;
  const float2* a2 = (const float2*)(aug2) + (size_t)row * 64;
  float2 v1 = a1[l], v2 = a2[l];
  float ss1 = v1.x * v1.x + v1.y * v1.y;
  float ss2 = v2.x * v2.x + v2.y * v2.y;
  float dp = v1.x * v2.x + v1.y * v2.y;
#pragma unroll
  for (int off = 1; off < 64; off <<= 1) {
    ss1 += __shfl_xor(ss1, off);
    ss2 += __shfl_xor(ss2, off);
    dp += __shfl_xor(dp, off);
  }
  float inv1 = 1.0f / fmaxf(sqrtf(ss1), 1e-8f);
  float inv2 = 1.0f / fmaxf(sqrtf(ss2), 1e-8f);
  bf16x2 o1, o2;
  o1[0] = (__bf16)(v1.x * inv1);
  o1[1] = (__bf16)(v1.y * inv1);
  o2[0] = (__bf16)(v2.x * inv2);
  o2[1] = (__bf16)(v2.y * inv2);
  ((bf16x2*)(an))[(size_t)row * 64 + l] = o1;
  ((bf16x2*)(an + (size_t)NB * ND))[(size_t)row * 64 + l] = o2;
  if (l == 0) pos[row] = dp * inv1 * inv2;
}

// Branchless "insert v into ascending top-10 list": identity when v <= t[0].
__device__ __forceinline__ void insert10(float t[10], float v) {
#pragma unroll
  for (int j = 0; j < 9; ++j) t[j] = fmaxf(t[j], fminf(t[j + 1], v));
  t[9] = fmaxf(t[9], v);
}

__device__ __forceinline__ void insert10g(float t[10], float v) {
  if (v > t[0]) insert10(t, v);
}

// ---------------------------------------------------------------------------
// Kernel 2: fused Gram (An . An^T) + per-row top-10 (diag = -inf).
// Block = 256 thr (4 waves), 64 rows per block, half the column space
// (4096 cols) per block -> grid (128 rowgroups * 2 halves, 2 dirs) = 512.
// MFMA with SWAPPED operands: A-op = col frag, B-op = row frag, so
// D[m=col][n=row]: lane l holds row n = row_base+rb*16+(l&15) and cols
// m = cb + w*16 + (l>>4)*4 + r. Each lane keeps 4 private top-10 lists.
// ---------------------------------------------------------------------------
__global__ __launch_bounds__(256, 2) void kgram(const __bf16* __restrict__ an_all,
                                                float* __restrict__ tk) {
  int dir = blockIdx.y;
  int rowg = blockIdx.x >> 1;
  int half = blockIdx.x & 1;
  const bf16x8* an8 = (const bf16x8*)(an_all + (size_t)dir * NB * ND);
  int w = threadIdx.x >> 6;
  int l = threadIdx.x & 63;
  int q = l >> 4;
  int c = l & 15;
  int row_base = rowg * 64;

  // Row fragments (B-operand): B[k][n] = An[row_base+rb*16+n][k],
  // lane: n = l&15, k = q*8+j. Loaded once, K=128 = 4 chunks of 32.
  bf16x8 brow[4][4];
#pragma unroll
  for (int rb = 0; rb < 4; ++rb)
#pragma unroll
    for (int kc = 0; kc < 4; ++kc)
      brow[rb][kc] = an8[(row_base + rb * 16 + c) * 16 + kc * 4 + q];

  float t[4][10];
#pragma unroll
  for (int rb = 0; rb < 4; ++rb)
#pragma unroll
    for (int j = 0; j < 10; ++j) t[rb][j] = -__builtin_inff();

  const int col0 = half * 4096;
  const int colend = col0 + 4096;

  // Prefetch first column fragments (A-operand): A[m][k] = An[colw+m][k].
  bf16x8 a[4];
  {
    int colw = col0 + w * 16;
#pragma unroll
    for (int kc = 0; kc < 4; ++kc) a[kc] = an8[(colw + c) * 16 + kc * 4 + q];
  }

  for (int cb = col0; cb < colend; cb += 64) {
    f32x4 acc[4];
    const f32x4 zz = {0.f, 0.f, 0.f, 0.f};
#pragma unroll
    for (int rb = 0; rb < 4; ++rb)
      acc[rb] = __builtin_amdgcn_mfma_f32_16x16x32_bf16(a[0], brow[rb][0], zz, 0, 0, 0);
#pragma unroll
    for (int kc = 1; kc < 4; ++kc)
#pragma unroll
      for (int rb = 0; rb < 4; ++rb)
        acc[rb] = __builtin_amdgcn_mfma_f32_16x16x32_bf16(a[kc], brow[rb][kc], acc[rb], 0, 0, 0);

    // Software prefetch next iteration's column frags (hides L2 latency
    // behind the insert VALU work below).
    int cbn = (cb + 64 < colend) ? (cb + 64) : col0;
    int colwn = cbn + w * 16;
#pragma unroll
    for (int kc = 0; kc < 4; ++kc) a[kc] = an8[(colwn + c) * 16 + kc * 4 + q];

    int cq = cb + w * 16 + q * 4;
#pragma unroll
    for (int rb = 0; rb < 4; ++rb) {
      int myrow = row_base + rb * 16 + c;
#pragma unroll
      for (int r = 0; r < 4; ++r) {
        float v = acc[rb][r];
        v = (cq + r == myrow) ? -__builtin_inff() : v;  // mask diagonal
        insert10(t[rb], v);  // unconditional: wave-wide some lane nearly always fires
      }
    }
  }

  // Merge the 16 sublists per row (4 waves x 4 quads).
  __shared__ float mg[64][16][10];
#pragma unroll
  for (int rb = 0; rb < 4; ++rb)
#pragma unroll
    for (int j = 0; j < 10; ++j) mg[rb * 16 + c][w * 4 + q][j] = t[rb][j];
  __syncthreads();

  // Stage 1: 256 threads; thread (g, rl) merges lists g*4..g*4+3 of row rl.
  {
    int rl = threadIdx.x & 63;
    int g = threadIdx.x >> 6;
    float cur[10];
#pragma unroll
    for (int j = 0; j < 10; ++j) cur[j] = mg[rl][g * 4][j];
#pragma unroll
    for (int s = 1; s < 4; ++s)
#pragma unroll
      for (int j = 0; j < 10; ++j) insert10g(cur, mg[rl][g * 4 + s][j]);
#pragma unroll
    for (int j = 0; j < 10; ++j) mg[rl][g * 4][j] = cur[j];
  }
  __syncthreads();

  // Stage 2: 64 threads; merge the 4 group lists, write ascending top-10.
  if (threadIdx.x < 64) {
    int rl = threadIdx.x;
    float cur[10];
#pragma unroll
    for (int j = 0; j < 10; ++j) cur[j] = mg[rl][0][j];
#pragma unroll
    for (int s = 1; s < 4; ++s)
#pragma unroll
      for (int j = 0; j < 10; ++j) insert10g(cur, mg[rl][s * 4][j]);
    float* o = tk + (((size_t)dir * NB + row_base + rl) * 2 + half) * 10;
#pragma unroll
    for (int j = 0; j < 10; ++j) o[j] = cur[j];
  }
}

// ---------------------------------------------------------------------------
// Kernel 3: merge the two half-lists, append pos_sim, run the unrolled
// odd-even soft sort (n=11) with P[11][11] in registers, BCE, atomic sum.
// One thread per (dir,row).
// ---------------------------------------------------------------------------
__global__ __launch_bounds__(256, 1) void ksort(const float* __restrict__ tk,
                                                const float* __restrict__ pos,
                                                float* __restrict__ out) {
  int tid = blockIdx.x * 256 + threadIdx.x;
  int dir = tid >> 13;
  int row = tid & (NB - 1);
  const float* A = tk + ((size_t)(dir * NB + row) * 2) * 10;

  float s10[10];
#pragma unroll
  for (int j = 0; j < 10; ++j) s10[j] = A[j];
#pragma unroll
  for (int j = 0; j < 10; ++j) insert10g(s10, A[10 + j]);

  float x[11];
#pragma unroll
  for (int j = 0; j < 10; ++j) x[j] = s10[j];  // negs ascending
  x[10] = pos[row];                            // positive appended

  float P[11][11];
#pragma unroll
  for (int i = 0; i < 11; ++i)
#pragma unroll
    for (int j = 0; j < 11; ++j) P[i][j] = (i == j) ? 1.f : 0.f;

#pragma unroll
  for (int layer = 0; layer < 11; ++layer) {
#pragma unroll
    for (int ii = (layer & 1); ii + 1 < 11; ii += 2) {
      float av = x[ii], bv = x[ii + 1];
      float alpha = atanf(bv - av) * 0.3183098861837907f + 0.5f;
      float be = 1.f - alpha;
      x[ii] = alpha * av + be * bv;
      x[ii + 1] = be * av + alpha * bv;
#pragma unroll
      for (int rr = 0; rr < 11; ++rr) {
        float Pa = P[rr][ii], Pb = P[rr][ii + 1];
        P[rr][ii] = alpha * Pa + be * Pb;
        P[rr][ii + 1] = be * Pa + alpha * Pb;
      }
    }
  }

  float C = 0.f;
#pragma unroll
  for (int i = 0; i < 11; ++i) {
    float pn = 0.f;
#pragma unroll
    for (int j = 0; j < 10; ++j) pn += P[i][j];
    float pp = P[i][10];
    pn = fminf(fmaxf(pn, 0.f), 1.f);
    pp = fminf(fmaxf(pp, 0.f), 1.f);
    float lp_pp = fmaxf(logf(pp), -100.f);
    float l1_pp = fmaxf(logf(1.f - pp), -100.f);
    float lp_pn = fmaxf(logf(pn), -100.f);
    float l1_pn = fmaxf(logf(1.f - pn), -100.f);
    C += (i < 10) ? (l1_pp + lp_pn) : (lp_pp + l1_pn);
  }
#pragma unroll
  for (int off = 1; off < 64; off <<= 1) C += __shfl_xor(C, off);
  if ((threadIdx.x & 63) == 0)
    atomicAdd(out, C * (-1.f / (4.f * (float)NB * 11.f)));
}

// ---------------------------------------------------------------------------
// ws layout: [an1 bf16 2MB][an2 bf16 2MB][pos f32 32KB][tk f32 1.25MB]
// ---------------------------------------------------------------------------
extern "C" void kernel_launch(void* const* d_in, const int* in_sizes, int n_in,
                              void* d_out, int out_size, void* d_ws, size_t ws_size,
                              hipStream_t stream) {
  const float* aug1 = (const float*)d_in[0];
  const float* aug2 = (const float*)d_in[1];
  char* w = (char*)d_ws;
  __bf16* an = (__bf16*)w;                              // 2 dirs contiguous
  float* pos = (float*)(w + (size_t)4 * 1024 * 1024);   // NB floats
  float* tk = pos + NB;                                 // 2*NB*2*10 floats

  hipMemsetAsync(d_out, 0, sizeof(float), stream);
  knorm<<<dim3(NB / 4), dim3(256), 0, stream>>>(aug1, aug2, an, pos);
  kgram<<<dim3(256, 2), dim3(256), 0, stream>>>(an, tk);
  ksort<<<dim3(2 * NB / 256), dim3(256), 0, stream>>>(tk, pos, (float*)d_out);
}

// Round 3
// 185.038 us; speedup vs baseline: 1.0209x; 1.0209x over previous
//
#include <hip/hip_runtime.h>
#include <cstdint>
#include <cmath>

#define NB 8192
#define ND 128
#define NEG_INF (-__builtin_inff())

typedef __attribute__((ext_vector_type(8))) __bf16 bf16x8;
typedef __attribute__((ext_vector_type(2))) __bf16 bf16x2;
typedef __attribute__((ext_vector_type(4))) float f32x4;

// Insert v into ascending top-10 list. med3(t[j], t[j+1], v) == the classic
// max(t[j], min(t[j+1], v)) when t ascending -> 10 VALU ops instead of 19.
__device__ __forceinline__ void insert10(float t[10], float v) {
#pragma unroll
  for (int j = 0; j < 9; ++j) t[j] = __builtin_amdgcn_fmed3f(t[j], t[j + 1], v);
  t[9] = fmaxf(t[9], v);
}

// ---------------------------------------------------------------------------
// Soft odd-even sort (n=11) + BCE row term, shared by ksort and kfallback.
// Returns C_row = sum of log-terms; caller scales by -1/(4*NB*11).
// ---------------------------------------------------------------------------
__device__ float row_loss(float x[11]) {
  float P[11][11];
#pragma unroll
  for (int i = 0; i < 11; ++i)
#pragma unroll
    for (int j = 0; j < 11; ++j) P[i][j] = (i == j) ? 1.f : 0.f;

#pragma unroll
  for (int layer = 0; layer < 11; ++layer) {
#pragma unroll
    for (int ii = (layer & 1); ii + 1 < 11; ii += 2) {
      float av = x[ii], bv = x[ii + 1];
      float alpha = atanf(bv - av) * 0.3183098861837907f + 0.5f;
      float be = 1.f - alpha;
      x[ii] = alpha * av + be * bv;
      x[ii + 1] = be * av + alpha * bv;
#pragma unroll
      for (int rr = 0; rr < 11; ++rr) {
        float Pa = P[rr][ii], Pb = P[rr][ii + 1];
        P[rr][ii] = alpha * Pa + be * Pb;
        P[rr][ii + 1] = be * Pa + alpha * Pb;
      }
    }
  }

  float C = 0.f;
#pragma unroll
  for (int i = 0; i < 11; ++i) {
    float pn = 0.f;
#pragma unroll
    for (int j = 0; j < 10; ++j) pn += P[i][j];
    float pp = P[i][10];
    pn = fminf(fmaxf(pn, 0.f), 1.f);
    pp = fminf(fmaxf(pp, 0.f), 1.f);
    float lp_pp = fmaxf(logf(pp), -100.f);
    float l1_pp = fmaxf(logf(1.f - pp), -100.f);
    float lp_pn = fmaxf(logf(pn), -100.f);
    float l1_pn = fmaxf(logf(1.f - pn), -100.f);
    C += (i < 10) ? (l1_pp + lp_pn) : (lp_pp + l1_pn);
  }
  return C;
}

// ---------------------------------------------------------------------------
// Kernel 1: row-normalize aug1/aug2 -> bf16, plus fp32 pos_sims.
// ---------------------------------------------------------------------------
__global__ __launch_bounds__(256, 4) void knorm(const float* __restrict__ aug1,
                                                const float* __restrict__ aug2,
                                                __bf16* __restrict__ an,
                                                float* __restrict__ pos) {
  int wid = threadIdx.x >> 6;
  int l = threadIdx.x & 63;
  int row = blockIdx.x * 4 + wid;
  const float2* a1 = (const float2*)(aug1) + (size_t)row * 64;
  const float2* a2 = (const float2*)(aug2) + (size_t)row * 64;
  float2 v1 = a1[l], v2 = a2[l];
  float ss1 = v1.x * v1.x + v1.y * v1.y;
  float ss2 = v2.x * v2.x + v2.y * v2.y;
  float dp = v1.x * v2.x + v1.y * v2.y;
#pragma unroll
  for (int off = 1; off < 64; off <<= 1) {
    ss1 += __shfl_xor(ss1, off);
    ss2 += __shfl_xor(ss2, off);
    dp += __shfl_xor(dp, off);
  }
  float inv1 = 1.0f / fmaxf(sqrtf(ss1), 1e-8f);
  float inv2 = 1.0f / fmaxf(sqrtf(ss2), 1e-8f);
  bf16x2 o1, o2;
  o1[0] = (__bf16)(v1.x * inv1);
  o1[1] = (__bf16)(v1.y * inv1);
  o2[0] = (__bf16)(v2.x * inv2);
  o2[1] = (__bf16)(v2.y * inv2);
  ((bf16x2*)(an))[(size_t)row * 64 + l] = o1;
  ((bf16x2*)(an + (size_t)NB * ND))[(size_t)row * 64 + l] = o2;
  if (l == 0) pos[row] = dp * inv1 * inv2;
}

// ---------------------------------------------------------------------------
// Kernel 2: pooled sim statistics from a sample (64 rows x 2048 cols per dir).
// Rows are isotropic unit vectors => sim variance identical for all rows, so
// one pooled (mu, sigma) is valid. stats = {n, sum, sumsq}.
// ---------------------------------------------------------------------------
__global__ __launch_bounds__(256) void kstats(const __bf16* __restrict__ an_all,
                                              float* __restrict__ stats) {
  int dir = blockIdx.y;
  int row = blockIdx.x * 128 + 63;
  const __bf16* an = an_all + (size_t)dir * NB * ND;
  __shared__ float rv[128];
  if (threadIdx.x < 64) {
    bf16x2 p = ((const bf16x2*)an)[(size_t)row * 64 + threadIdx.x];
    rv[threadIdx.x * 2] = (float)p[0];
    rv[threadIdx.x * 2 + 1] = (float)p[1];
  }
  __syncthreads();
  float s1 = 0.f, s2 = 0.f, n = 0.f;
  for (int i = 0; i < 8; ++i) {
    int col = threadIdx.x + i * 256;  // cols 0..2047
    if (col == row) continue;
    const bf16x8* cp = (const bf16x8*)(an + (size_t)col * ND);
    float d = 0.f;
#pragma unroll
    for (int k = 0; k < 16; ++k) {
      bf16x8 p = cp[k];
#pragma unroll
      for (int e = 0; e < 8; ++e) d = fmaf(rv[k * 8 + e], (float)p[e], d);
    }
    s1 += d;
    s2 = fmaf(d, d, s2);
    n += 1.f;
  }
#pragma unroll
  for (int off = 1; off < 64; off <<= 1) {
    s1 += __shfl_xor(s1, off);
    s2 += __shfl_xor(s2, off);
    n += __shfl_xor(n, off);
  }
  __shared__ float red[3][4];
  if ((threadIdx.x & 63) == 0) {
    int wv = threadIdx.x >> 6;
    red[0][wv] = n; red[1][wv] = s1; red[2][wv] = s2;
  }
  __syncthreads();
  if (threadIdx.x == 0) {
    atomicAdd(stats + 0, red[0][0] + red[0][1] + red[0][2] + red[0][3]);
    atomicAdd(stats + 1, red[1][0] + red[1][1] + red[1][2] + red[1][3]);
    atomicAdd(stats + 2, red[2][0] + red[2][1] + red[2][2] + red[2][3]);
  }
}

// ---------------------------------------------------------------------------
// Kernel 3: fused Gram + threshold-filtered per-row top-10 + survivor count.
// MFMA swapped operands: lane holds row (l&15), 4 cols -> private lists.
// ---------------------------------------------------------------------------
template <bool DIAG>
__device__ __forceinline__ void consume(const f32x4* acc, float (*t)[10], int* cnt,
                                        float tau, int cq, int row_base, int c) {
#pragma unroll
  for (int rb = 0; rb < 4; ++rb) {
    int myrow = row_base + rb * 16 + c;
#pragma unroll
    for (int r = 0; r < 4; ++r) {
      float v = acc[rb][r];
      if (DIAG) v = (cq + r == myrow) ? NEG_INF : v;
      if (v > tau) {  // exec-mask branch; survivors ~0.6% of slots
        ++cnt[rb];
        insert10(t[rb], v);
      }
    }
  }
}

__global__ __launch_bounds__(256, 2) void kgram(const __bf16* __restrict__ an_all,
                                                float* __restrict__ tk,
                                                int* __restrict__ cnt_g,
                                                const float* __restrict__ stats) {
  int dir = blockIdx.y;
  int rowg = blockIdx.x >> 1;
  int half = blockIdx.x & 1;
  const bf16x8* an8 = (const bf16x8*)(an_all + (size_t)dir * NB * ND);
  int w = threadIdx.x >> 6;
  int l = threadIdx.x & 63;
  int q = l >> 4;
  int c = l & 15;
  int row_base = rowg * 64;

  float n = stats[0], s1 = stats[1], s2 = stats[2];
  float mu = s1 / n;
  float sig = sqrtf(fmaxf(s2 / n - mu * mu, 0.f));
  float tau = mu + 2.5f * sig;  // lambda ~46 survivors/row; P(count<10) ~ 1e-11

  bf16x8 brow[4][4];
#pragma unroll
  for (int rb = 0; rb < 4; ++rb)
#pragma unroll
    for (int kc = 0; kc < 4; ++kc)
      brow[rb][kc] = an8[(row_base + rb * 16 + c) * 16 + kc * 4 + q];

  float t[4][10];
#pragma unroll
  for (int rb = 0; rb < 4; ++rb)
#pragma unroll
    for (int j = 0; j < 10; ++j) t[rb][j] = NEG_INF;
  int cnt[4] = {0, 0, 0, 0};

  const int col0 = half * 4096;
  const int colend = col0 + 4096;

  bf16x8 a[4];
  {
    int colw = col0 + w * 16;
#pragma unroll
    for (int kc = 0; kc < 4; ++kc) a[kc] = an8[(colw + c) * 16 + kc * 4 + q];
  }

  for (int cb = col0; cb < colend; cb += 64) {
    f32x4 acc[4];
    const f32x4 zz = {0.f, 0.f, 0.f, 0.f};
#pragma unroll
    for (int rb = 0; rb < 4; ++rb)
      acc[rb] = __builtin_amdgcn_mfma_f32_16x16x32_bf16(a[0], brow[rb][0], zz, 0, 0, 0);
#pragma unroll
    for (int kc = 1; kc < 4; ++kc)
#pragma unroll
      for (int rb = 0; rb < 4; ++rb)
        acc[rb] = __builtin_amdgcn_mfma_f32_16x16x32_bf16(a[kc], brow[rb][kc], acc[rb], 0, 0, 0);

    int cbn = (cb + 64 < colend) ? (cb + 64) : col0;
    int colwn = cbn + w * 16;
#pragma unroll
    for (int kc = 0; kc < 4; ++kc) a[kc] = an8[(colwn + c) * 16 + kc * 4 + q];

    int cq = cb + w * 16 + q * 4;
    if (cb == row_base)  // block-uniform: only col-block containing the diagonal
      consume<true>(acc, t, cnt, tau, cq, row_base, c);
    else
      consume<false>(acc, t, cnt, tau, cq, row_base, c);
  }

  // Merge 16 sublists/row. Row-stride 11 floats: coprime with 32 banks.
  __shared__ float mg[16][64][11];
  __shared__ int mc[16][64];
  int sub = w * 4 + q;
#pragma unroll
  for (int rb = 0; rb < 4; ++rb) {
    int rl = rb * 16 + c;
#pragma unroll
    for (int j = 0; j < 10; ++j) mg[sub][rl][j] = t[rb][j];
    mc[sub][rl] = cnt[rb];
  }
  __syncthreads();
  {
    int rl = threadIdx.x & 63;
    int g = threadIdx.x >> 6;
    float cur[10];
#pragma unroll
    for (int j = 0; j < 10; ++j) cur[j] = mg[g * 4][rl][j];
    int cc = mc[g * 4][rl];
#pragma unroll
    for (int s = 1; s < 4; ++s) {
      cc += mc[g * 4 + s][rl];
#pragma unroll
      for (int j = 0; j < 10; ++j) {
        float v = mg[g * 4 + s][rl][j];
        if (v > cur[0]) insert10(cur, v);
      }
    }
#pragma unroll
    for (int j = 0; j < 10; ++j) mg[g * 4][rl][j] = cur[j];
    mc[g * 4][rl] = cc;
  }
  __syncthreads();
  if (threadIdx.x < 64) {
    int rl = threadIdx.x;
    float cur[10];
#pragma unroll
    for (int j = 0; j < 10; ++j) cur[j] = mg[0][rl][j];
    int cc = mc[0][rl];
#pragma unroll
    for (int g = 1; g < 4; ++g) {
      cc += mc[g * 4][rl];
#pragma unroll
      for (int j = 0; j < 10; ++j) {
        float v = mg[g * 4][rl][j];
        if (v > cur[0]) insert10(cur, v);
      }
    }
    float* o = tk + (((size_t)dir * NB + row_base + rl) * 2 + half) * 10;
#pragma unroll
    for (int j = 0; j < 10; ++j) o[j] = cur[j];
    atomicAdd(cnt_g + dir * NB + row_base + rl, cc);
  }
}

// ---------------------------------------------------------------------------
// Kernel 4: merge half-lists, soft-sort, BCE. Skips rows with count<10.
// ---------------------------------------------------------------------------
__global__ __launch_bounds__(64) void ksort(const float* __restrict__ tk,
                                            const float* __restrict__ pos,
                                            const int* __restrict__ cnt_g,
                                            float* __restrict__ out) {
  int tid = blockIdx.x * 64 + threadIdx.x;
  int dir = tid >> 13;
  int row = tid & (NB - 1);
  float C = 0.f;
  if (cnt_g[dir * NB + row] >= 10) {
    const float* A = tk + ((size_t)(dir * NB + row) * 2) * 10;
    float s10[10];
#pragma unroll
    for (int j = 0; j < 10; ++j) s10[j] = A[j];
#pragma unroll
    for (int j = 0; j < 10; ++j) {
      float v = A[10 + j];
      if (v > s10[0]) insert10(s10, v);
    }
    float x[11];
#pragma unroll
    for (int j = 0; j < 10; ++j) x[j] = s10[j];
    x[10] = pos[row];
    C = row_loss(x);
  }
#pragma unroll
  for (int off = 1; off < 64; off <<= 1) C += __shfl_xor(C, off);
  if (threadIdx.x == 0) atomicAdd(out, C * (-1.f / (4.f * (float)NB * 11.f)));
}

// ---------------------------------------------------------------------------
// Kernel 5: exact brute-force fallback for rows with count<10. Parallel flag
// gather: 64 blocks x 256 threads covers all 2*NB gids with ONE load each
// (no serial dependent-load scan). Normally the work list is empty and the
// kernel exits immediately; correctness never depends on the statistics.
// ---------------------------------------------------------------------------
__global__ __launch_bounds__(256) void kfallback(const __bf16* __restrict__ an_all,
                                                 const int* __restrict__ cnt_g,
                                                 const float* __restrict__ pos,
                                                 float* __restrict__ out) {
  __shared__ int work[256];
  __shared__ int nwork;
  __shared__ float rv[128];
  __shared__ float lists[256][10];
  if (threadIdx.x == 0) nwork = 0;
  __syncthreads();
  int gid0 = blockIdx.x * 256 + threadIdx.x;  // 64*256 == 2*NB exactly
  if (cnt_g[gid0] < 10) {
    int s = atomicAdd(&nwork, 1);
    work[s] = gid0;
  }
  __syncthreads();
  int nw = nwork;
  for (int it = 0; it < nw; ++it) {
    int gid = work[it];
    int dir = gid >> 13, row = gid & (NB - 1);
    const __bf16* an = an_all + (size_t)dir * NB * ND;
    __syncthreads();
    if (threadIdx.x < 64) {
      bf16x2 p = ((const bf16x2*)an)[(size_t)row * 64 + threadIdx.x];
      rv[threadIdx.x * 2] = (float)p[0];
      rv[threadIdx.x * 2 + 1] = (float)p[1];
    }
    __syncthreads();
    float t[10];
#pragma unroll
    for (int j = 0; j < 10; ++j) t[j] = NEG_INF;
    for (int i = 0; i < 32; ++i) {
      int col = threadIdx.x + i * 256;
      if (col == row) continue;
      const bf16x8* cp = (const bf16x8*)(an + (size_t)col * ND);
      float d = 0.f;
#pragma unroll
      for (int k = 0; k < 16; ++k) {
        bf16x8 p = cp[k];
#pragma unroll
        for (int e = 0; e < 8; ++e) d = fmaf(rv[k * 8 + e], (float)p[e], d);
      }
      if (d > t[0]) insert10(t, d);
    }
#pragma unroll
    for (int j = 0; j < 10; ++j) lists[threadIdx.x][j] = t[j];
    __syncthreads();
    if (threadIdx.x == 0) {
      float cur[10];
#pragma unroll
      for (int j = 0; j < 10; ++j) cur[j] = lists[0][j];
      for (int s = 1; s < 256; ++s)
        for (int j = 0; j < 10; ++j) {
          float v = lists[s][j];
          if (v > cur[0]) insert10(cur, v);
        }
      float x[11];
#pragma unroll
      for (int j = 0; j < 10; ++j) x[j] = cur[j];
      x[10] = pos[row];
      atomicAdd(out, row_loss(x) * (-1.f / (4.f * (float)NB * 11.f)));
    }
    __syncthreads();
  }
}

// ---------------------------------------------------------------------------
// ws: [an bf16 4MB][pos f32 32KB][tk f32 2.62MB][cnt i32 64KB][stats f32 16B]
// ---------------------------------------------------------------------------
extern "C" void kernel_launch(void* const* d_in, const int* in_sizes, int n_in,
                              void* d_out, int out_size, void* d_ws, size_t ws_size,
                              hipStream_t stream) {
  const float* aug1 = (const float*)d_in[0];
  const float* aug2 = (const float*)d_in[1];
  char* w = (char*)d_ws;
  __bf16* an = (__bf16*)w;
  float* pos = (float*)(w + (size_t)4 * 1024 * 1024);
  float* tk = pos + NB;
  int* cnt = (int*)(tk + (size_t)2 * NB * 2 * 10);
  float* stats = (float*)(cnt + 2 * NB);

  hipMemsetAsync(d_out, 0, sizeof(float), stream);
  hipMemsetAsync(cnt, 0, (size_t)2 * NB * 4 + 16, stream);
  knorm<<<dim3(NB / 4), dim3(256), 0, stream>>>(aug1, aug2, an, pos);
  kstats<<<dim3(64, 2), dim3(256), 0, stream>>>(an, stats);
  kgram<<<dim3(256, 2), dim3(256), 0, stream>>>(an, tk, cnt, stats);
  ksort<<<dim3(2 * NB / 64), dim3(64), 0, stream>>>(tk, pos, cnt, (float*)d_out);
  kfallback<<<dim3(64), dim3(256), 0, stream>>>(an, cnt, pos, (float*)d_out);
}

// Round 5
// 143.823 us; speedup vs baseline: 1.3135x; 1.2866x over previous
//
#include <hip/hip_runtime.h>
#include <cstdint>
#include <cmath>

#define NB 8192
#define ND 128
#define CAP 64
#define NEG_INF (-__builtin_inff())

typedef __attribute__((ext_vector_type(8))) __bf16 bf16x8;
typedef __attribute__((ext_vector_type(2))) __bf16 bf16x2;
typedef __attribute__((ext_vector_type(4))) float f32x4;

// Insert v into ascending top-10 list (identity when v <= t[0]).
__device__ __forceinline__ void insert10(float t[10], float v) {
#pragma unroll
  for (int j = 0; j < 9; ++j) t[j] = __builtin_amdgcn_fmed3f(t[j], t[j + 1], v);
  t[9] = fmaxf(t[9], v);
}

// ---------------------------------------------------------------------------
// Row loss via column-10-only soft sort. P is row-stochastic (convex row
// mixes starting from I) => p_neg = 1 - p_pos exactly, clips are no-ops, and
// BCE(p_neg,t_neg) == BCE(p_pos,t_pos). p_pos = P[:,10] = M_1(...(M_11 e10)).
// Forward stores 55 alphas; backward propagates an 11-vector.
// Returns sum_i [t_i log p_i + (1-t_i) log(1-p_i)] (terms clamped at -100);
// caller scales by -1/(2*NB*11).
// ---------------------------------------------------------------------------
__device__ float row_loss(float x[11]) {
  float al[55];
#pragma unroll
  for (int layer = 0; layer < 11; ++layer) {
#pragma unroll
    for (int p = 0; p < 5; ++p) {
      int ii = (layer & 1) + 2 * p;
      float av = x[ii], bv = x[ii + 1];
      float a = atanf(bv - av) * 0.3183098861837907f + 0.5f;
      al[layer * 5 + p] = a;
      float be = 1.f - a;
      x[ii] = a * av + be * bv;
      x[ii + 1] = be * av + a * bv;
    }
  }
  float v[11];
#pragma unroll
  for (int i = 0; i < 11; ++i) v[i] = 0.f;
  v[10] = 1.f;
#pragma unroll
  for (int layer = 10; layer >= 0; --layer) {
#pragma unroll
    for (int p = 0; p < 5; ++p) {
      int ii = (layer & 1) + 2 * p;
      float a = al[layer * 5 + p];
      float be = 1.f - a;
      float va = v[ii], vb = v[ii + 1];
      v[ii] = a * va + be * vb;
      v[ii + 1] = be * va + a * vb;
    }
  }
  float C = fmaxf(logf(v[10]), -100.f);
#pragma unroll
  for (int i = 0; i < 10; ++i) C += fmaxf(logf(1.f - v[i]), -100.f);
  return C;
}

// ---------------------------------------------------------------------------
// Kernel 1: row-normalize aug1/aug2 -> bf16, plus fp32 pos_sims.
// ---------------------------------------------------------------------------
__global__ __launch_bounds__(256, 4) void knorm(const float* __restrict__ aug1,
                                                const float* __restrict__ aug2,
                                                __bf16* __restrict__ an,
                                                float* __restrict__ pos) {
  int wid = threadIdx.x >> 6;
  int l = threadIdx.x & 63;
  int row = blockIdx.x * 4 + wid;
  const float2* a1 = (const float2*)(aug1) + (size_t)row * 64;
  const float2* a2 = (const float2*)(aug2) + (size_t)row * 64;
  float2 v1 = a1[l], v2 = a2[l];
  float ss1 = v1.x * v1.x + v1.y * v1.y;
  float ss2 = v2.x * v2.x + v2.y * v2.y;
  float dp = v1.x * v2.x + v1.y * v2.y;
#pragma unroll
  for (int off = 1; off < 64; off <<= 1) {
    ss1 += __shfl_xor(ss1, off);
    ss2 += __shfl_xor(ss2, off);
    dp += __shfl_xor(dp, off);
  }
  float inv1 = 1.0f / fmaxf(sqrtf(ss1), 1e-8f);
  float inv2 = 1.0f / fmaxf(sqrtf(ss2), 1e-8f);
  bf16x2 o1, o2;
  o1[0] = (__bf16)(v1.x * inv1);
  o1[1] = (__bf16)(v1.y * inv1);
  o2[0] = (__bf16)(v2.x * inv2);
  o2[1] = (__bf16)(v2.y * inv2);
  ((bf16x2*)(an))[(size_t)row * 64 + l] = o1;
  ((bf16x2*)(an + (size_t)NB * ND))[(size_t)row * 64 + l] = o2;
  if (l == 0) pos[row] = dp * inv1 * inv2;
}

// ---------------------------------------------------------------------------
// Survivor append: survivors (~0.6% of sims) go to per-row LDS candidate
// buffers via ds-atomic slots (no per-lane sorted lists -> no spills).
// ---------------------------------------------------------------------------
template <bool DIAG>
__device__ __forceinline__ void consume(const f32x4* acc, float (*cand)[CAP],
                                        int* lcnt, float tau, int cq,
                                        int row_base, int c) {
#pragma unroll
  for (int rb = 0; rb < 4; ++rb) {
    int rl = rb * 16 + c;
#pragma unroll
    for (int r = 0; r < 4; ++r) {
      float v = acc[rb][r];
      if (DIAG) v = (cq + r == row_base + rl) ? NEG_INF : v;
      if (v > tau) {
        int s = atomicAdd(&lcnt[rl], 1);
        if (s < CAP) cand[rl][s] = v;
      }
    }
  }
}

// ---------------------------------------------------------------------------
// Kernel 2: fused Gram + self-calibrating threshold filter.
// Block: 4 waves, 64 rows x 4096 cols (one half). Stats from the block's own
// iter-0 tile -> tau = mu + 2.5 sigma. tau stored so ksort can verify
// exactness: 10th-largest >= max(tau_h0, tau_h1) proves true top-10.
// ---------------------------------------------------------------------------
__global__ __launch_bounds__(256, 3) void kgram(const __bf16* __restrict__ an_all,
                                                float* __restrict__ tk,
                                                int* __restrict__ flags,
                                                float* __restrict__ taug) {
  int dir = blockIdx.y;
  int rowg = blockIdx.x >> 1;
  int half = blockIdx.x & 1;
  const bf16x8* an8 = (const bf16x8*)(an_all + (size_t)dir * NB * ND);
  int w = threadIdx.x >> 6;
  int l = threadIdx.x & 63;
  int q = l >> 4;
  int c = l & 15;
  int row_base = rowg * 64;
  const int col0 = half * 4096;
  const int colend = col0 + 4096;

  __shared__ float cand[64][CAP];
  __shared__ int lcnt[64];
  __shared__ float sred[2][4];
  if (threadIdx.x < 64) lcnt[threadIdx.x] = 0;

  // Row fragments (MFMA B-operand): B[k][n], lane n=c, unit index kc*4+q.
  bf16x8 brow[4][4];
#pragma unroll
  for (int rb = 0; rb < 4; ++rb)
#pragma unroll
    for (int kc = 0; kc < 4; ++kc)
      brow[rb][kc] = an8[(size_t)(row_base + rb * 16 + c) * 16 + kc * 4 + q];

  // Column-fragment pointer (A-operand): unit offset (col+c)*16 + kc*4 + q.
  // R4 bug was "+ q*4" here -> wrong K-slices for q!=0 lanes.
  const bf16x8* pf0 = an8 + ((size_t)(col0 + w * 16 + c) * 16 + q);
  const bf16x8* pf = pf0;
  bf16x8 a[4];
#pragma unroll
  for (int kc = 0; kc < 4; ++kc) a[kc] = pf[kc * 4];
  pf = pf0 + 1024;

  const f32x4 zz = {0.f, 0.f, 0.f, 0.f};
  f32x4 acc[4];

  // ---- iter 0: compute tile, derive stats, then consume it ----
#pragma unroll
  for (int rb = 0; rb < 4; ++rb)
    acc[rb] = __builtin_amdgcn_mfma_f32_16x16x32_bf16(a[0], brow[rb][0], zz, 0, 0, 0);
#pragma unroll
  for (int kc = 1; kc < 4; ++kc)
#pragma unroll
    for (int rb = 0; rb < 4; ++rb)
      acc[rb] = __builtin_amdgcn_mfma_f32_16x16x32_bf16(a[kc], brow[rb][kc], acc[rb], 0, 0, 0);
#pragma unroll
  for (int kc = 0; kc < 4; ++kc) a[kc] = pf[kc * 4];  // prefetch tile 1
  pf += 1024;

  bool diag0 = (row_base == col0);
  int cq0 = col0 + w * 16 + q * 4;
  float s1 = 0.f, s2 = 0.f;
#pragma unroll
  for (int rb = 0; rb < 4; ++rb) {
    int myrow = row_base + rb * 16 + c;
#pragma unroll
    for (int r = 0; r < 4; ++r) {
      float v = acc[rb][r];
      v = (diag0 && (cq0 + r == myrow)) ? 0.f : v;
      s1 += v;
      s2 = fmaf(v, v, s2);
    }
  }
#pragma unroll
  for (int off = 1; off < 64; off <<= 1) {
    s1 += __shfl_xor(s1, off);
    s2 += __shfl_xor(s2, off);
  }
  if (l == 0) { sred[0][w] = s1; sred[1][w] = s2; }
  __syncthreads();
  float n = diag0 ? 4032.f : 4096.f;
  float ts1 = sred[0][0] + sred[0][1] + sred[0][2] + sred[0][3];
  float ts2 = sred[1][0] + sred[1][1] + sred[1][2] + sred[1][3];
  float mu = ts1 / n;
  float sig = sqrtf(fmaxf(ts2 / n - mu * mu, 0.f));
  float tau = mu + 2.5f * sig;
  if (threadIdx.x == 0) taug[(dir * 128 + rowg) * 2 + half] = tau;

  if (diag0) consume<true>(acc, cand, lcnt, tau, cq0, row_base, c);
  else       consume<false>(acc, cand, lcnt, tau, cq0, row_base, c);

  // ---- main loop over remaining 63 col tiles ----
  for (int cb = col0 + 64; cb < colend; cb += 64) {
#pragma unroll
    for (int rb = 0; rb < 4; ++rb)
      acc[rb] = __builtin_amdgcn_mfma_f32_16x16x32_bf16(a[0], brow[rb][0], zz, 0, 0, 0);
#pragma unroll
    for (int kc = 1; kc < 4; ++kc)
#pragma unroll
      for (int rb = 0; rb < 4; ++rb)
        acc[rb] = __builtin_amdgcn_mfma_f32_16x16x32_bf16(a[kc], brow[rb][kc], acc[rb], 0, 0, 0);

    const bf16x8* pfn = (cb + 64 < colend) ? pf : pf0;  // wrap: unused data
#pragma unroll
    for (int kc = 0; kc < 4; ++kc) a[kc] = pfn[kc * 4];
    pf = pfn + 1024;

    int cq = cb + w * 16 + q * 4;
    if (cb == row_base) consume<true>(acc, cand, lcnt, tau, cq, row_base, c);
    else                consume<false>(acc, cand, lcnt, tau, cq, row_base, c);
  }

  // ---- epilogue: top-10 per row from ~25 candidates ----
  __syncthreads();
  if (threadIdx.x < 64) {
    int rl = threadIdx.x;
    int cc = lcnt[rl];
    float t10[10];
#pragma unroll
    for (int j = 0; j < 10; ++j) t10[j] = NEG_INF;
    int m = cc < CAP ? cc : CAP;
    for (int i = 0; i < m; ++i) {
      float v = cand[rl][i];
      if (v > t10[0]) insert10(t10, v);
    }
    float* o = tk + ((size_t)(dir * NB + row_base + rl) * 2 + half) * 10;
#pragma unroll
    for (int j = 0; j < 10; ++j) o[j] = t10[j];
    if (cc > CAP) atomicAdd(flags + dir * NB + row_base + rl, 1);
  }
}

// ---------------------------------------------------------------------------
// Kernel 3: merge half-lists, verify exactness, soft-sort + BCE, with fused
// brute-force fallback for unverified rows (expected: none).
// Block = 64 threads = 1 wave; dir uniform per block.
// ---------------------------------------------------------------------------
__global__ __launch_bounds__(64, 1) void ksort(const float* __restrict__ tk,
                                               const float* __restrict__ pos,
                                               const int* __restrict__ flags,
                                               const float* __restrict__ taug,
                                               const __bf16* __restrict__ an_all,
                                               float* __restrict__ out) {
  int tid = blockIdx.x * 64 + threadIdx.x;
  int dir = tid >> 13;
  int row = tid & (NB - 1);
  int lane = threadIdx.x;

  const float* A = tk + (size_t)(dir * NB + row) * 20;
  float s10[10];
#pragma unroll
  for (int j = 0; j < 10; ++j) s10[j] = A[j];
#pragma unroll
  for (int j = 0; j < 10; ++j) {
    float v = A[10 + j];
    if (v > s10[0]) insert10(s10, v);
  }
  int rowg = row >> 6;
  float tmax = fmaxf(taug[(dir * 128 + rowg) * 2], taug[(dir * 128 + rowg) * 2 + 1]);
  bool ok = (flags[dir * NB + row] == 0) && (s10[0] >= tmax);

  float C = 0.f;
  if (ok) {
    float x[11];
#pragma unroll
    for (int j = 0; j < 10; ++j) x[j] = s10[j];
    x[10] = pos[row];
    C = row_loss(x);
  }
#pragma unroll
  for (int off = 1; off < 64; off <<= 1) C += __shfl_xor(C, off);
  if (lane == 0) atomicAdd(out, C * (-1.f / (2.f * (float)NB * 11.f)));

  // ---- exact fallback for rows the tau-proof didn't cover ----
  unsigned long long bad = __ballot(!ok);
  if (bad == 0ull) return;
  __shared__ float rv[128];
  __shared__ float lst[64][10];
  const __bf16* an = an_all + (size_t)dir * NB * ND;
  while (bad) {
    int b = __ffsll((long long)bad) - 1;
    bad &= bad - 1;
    int brow = (blockIdx.x * 64 + b) & (NB - 1);
    bf16x2 pr = ((const bf16x2*)an)[(size_t)brow * 64 + lane];
    rv[lane * 2] = (float)pr[0];
    rv[lane * 2 + 1] = (float)pr[1];
    __syncthreads();
    float t10[10];
#pragma unroll
    for (int j = 0; j < 10; ++j) t10[j] = NEG_INF;
    for (int i = 0; i < 128; ++i) {
      int col = lane + i * 64;
      if (col == brow) continue;
      const bf16x8* cp = (const bf16x8*)(an + (size_t)col * ND);
      float d = 0.f;
#pragma unroll
      for (int k = 0; k < 16; ++k) {
        bf16x8 p = cp[k];
#pragma unroll
        for (int e = 0; e < 8; ++e) d = fmaf(rv[k * 8 + e], (float)p[e], d);
      }
      if (d > t10[0]) insert10(t10, d);
    }
#pragma unroll
    for (int j = 0; j < 10; ++j) lst[lane][j] = t10[j];
    __syncthreads();
    if (lane == 0) {
      float cur[10];
#pragma unroll
      for (int j = 0; j < 10; ++j) cur[j] = lst[0][j];
      for (int s = 1; s < 64; ++s)
        for (int j = 0; j < 10; ++j) {
          float v = lst[s][j];
          if (v > cur[0]) insert10(cur, v);
        }
      float x[11];
#pragma unroll
      for (int j = 0; j < 10; ++j) x[j] = cur[j];
      x[10] = pos[brow];
      atomicAdd(out, row_loss(x) * (-1.f / (2.f * (float)NB * 11.f)));
    }
    __syncthreads();
  }
}

// ---------------------------------------------------------------------------
// ws: [an bf16 4MB][pos 32KB][tk 1.28MB][flags 64KB][taug 2KB]
// ---------------------------------------------------------------------------
extern "C" void kernel_launch(void* const* d_in, const int* in_sizes, int n_in,
                              void* d_out, int out_size, void* d_ws, size_t ws_size,
                              hipStream_t stream) {
  const float* aug1 = (const float*)d_in[0];
  const float* aug2 = (const float*)d_in[1];
  char* w = (char*)d_ws;
  __bf16* an = (__bf16*)w;
  float* pos = (float*)(w + (size_t)4 * 1024 * 1024);
  float* tk = pos + NB;
  int* flags = (int*)(tk + (size_t)2 * NB * 20);
  float* taug = (float*)(flags + 2 * NB);

  hipMemsetAsync(d_out, 0, sizeof(float), stream);
  hipMemsetAsync(flags, 0, (size_t)2 * NB * 4, stream);
  knorm<<<dim3(NB / 4), dim3(256), 0, stream>>>(aug1, aug2, an, pos);
  kgram<<<dim3(256, 2), dim3(256), 0, stream>>>(an, tk, flags, taug);
  ksort<<<dim3(2 * NB / 64), dim3(64), 0, stream>>>(tk, pos, flags, taug, an, (float*)d_out);
}

// Round 6
// 139.193 us; speedup vs baseline: 1.3572x; 1.0333x over previous
//
#include <hip/hip_runtime.h>
#include <cstdint>
#include <cmath>

#define NB 8192
#define ND 128
#define CAP 64
#define NEG_INF (-__builtin_inff())

typedef __attribute__((ext_vector_type(8))) __bf16 bf16x8;
typedef __attribute__((ext_vector_type(2))) __bf16 bf16x2;
typedef __attribute__((ext_vector_type(4))) float f32x4;

// Insert v into ascending top-K list (identity when v <= t[0]).
__device__ __forceinline__ void insert10(float t[10], float v) {
#pragma unroll
  for (int j = 0; j < 9; ++j) t[j] = __builtin_amdgcn_fmed3f(t[j], t[j + 1], v);
  t[9] = fmaxf(t[9], v);
}
__device__ __forceinline__ void insert11(float t[11], float v) {
#pragma unroll
  for (int j = 0; j < 10; ++j) t[j] = __builtin_amdgcn_fmed3f(t[j], t[j + 1], v);
  t[10] = fmaxf(t[10], v);
}

// ---------------------------------------------------------------------------
// Row loss via column-10-only soft sort (P row-stochastic => p_neg = 1-p_pos,
// clips no-ops, both BCEs identical). Verified exact in R3/R5 (absmax 0.0).
// ---------------------------------------------------------------------------
__device__ float row_loss(float x[11]) {
  float al[55];
#pragma unroll
  for (int layer = 0; layer < 11; ++layer) {
#pragma unroll
    for (int p = 0; p < 5; ++p) {
      int ii = (layer & 1) + 2 * p;
      float av = x[ii], bv = x[ii + 1];
      float a = atanf(bv - av) * 0.3183098861837907f + 0.5f;
      al[layer * 5 + p] = a;
      float be = 1.f - a;
      x[ii] = a * av + be * bv;
      x[ii + 1] = be * av + a * bv;
    }
  }
  float v[11];
#pragma unroll
  for (int i = 0; i < 11; ++i) v[i] = 0.f;
  v[10] = 1.f;
#pragma unroll
  for (int layer = 10; layer >= 0; --layer) {
#pragma unroll
    for (int p = 0; p < 5; ++p) {
      int ii = (layer & 1) + 2 * p;
      float a = al[layer * 5 + p];
      float be = 1.f - a;
      float va = v[ii], vb = v[ii + 1];
      v[ii] = a * va + be * vb;
      v[ii + 1] = be * va + a * vb;
    }
  }
  float C = fmaxf(logf(v[10]), -100.f);
#pragma unroll
  for (int i = 0; i < 10; ++i) C += fmaxf(logf(1.f - v[i]), -100.f);
  return C;
}

// ---------------------------------------------------------------------------
// Kernel 1: row-normalize -> bf16 + fp32 pos_sims. Block 0 zeroes d_out
// (kernel-boundary ordering on the stream makes this visible to ksort).
// ---------------------------------------------------------------------------
__global__ __launch_bounds__(256, 4) void knorm(const float* __restrict__ aug1,
                                                const float* __restrict__ aug2,
                                                __bf16* __restrict__ an,
                                                float* __restrict__ pos,
                                                float* __restrict__ out) {
  if (blockIdx.x == 0 && threadIdx.x == 0) out[0] = 0.f;
  int wid = threadIdx.x >> 6;
  int l = threadIdx.x & 63;
  int row = blockIdx.x * 4 + wid;
  const float2* a1 = (const float2*)(aug1) + (size_t)row * 64;
  const float2* a2 = (const float2*)(aug2) + (size_t)row * 64;
  float2 v1 = a1[l], v2 = a2[l];
  float ss1 = v1.x * v1.x + v1.y * v1.y;
  float ss2 = v2.x * v2.x + v2.y * v2.y;
  float dp = v1.x * v2.x + v1.y * v2.y;
#pragma unroll
  for (int off = 1; off < 64; off <<= 1) {
    ss1 += __shfl_xor(ss1, off);
    ss2 += __shfl_xor(ss2, off);
    dp += __shfl_xor(dp, off);
  }
  float inv1 = 1.0f / fmaxf(sqrtf(ss1), 1e-8f);
  float inv2 = 1.0f / fmaxf(sqrtf(ss2), 1e-8f);
  bf16x2 o1, o2;
  o1[0] = (__bf16)(v1.x * inv1);
  o1[1] = (__bf16)(v1.y * inv1);
  o2[0] = (__bf16)(v2.x * inv2);
  o2[1] = (__bf16)(v2.y * inv2);
  ((bf16x2*)(an))[(size_t)row * 64 + l] = o1;
  ((bf16x2*)(an + (size_t)NB * ND))[(size_t)row * 64 + l] = o2;
  if (l == 0) pos[row] = dp * inv1 * inv2;
}

// Unconditional (no diag mask) survivor append to per-row LDS buffers.
__device__ __forceinline__ void consume4(const f32x4* acc, float (*cand)[CAP],
                                         int* lcnt, float tau, int c) {
#pragma unroll
  for (int rb = 0; rb < 4; ++rb) {
    int rl = rb * 16 + c;
#pragma unroll
    for (int r = 0; r < 4; ++r) {
      float v = acc[rb][r];
      if (v > tau) {
        int s = atomicAdd(&lcnt[rl], 1);
        if (s < CAP) cand[rl][s] = v;
      }
    }
  }
}

// ---------------------------------------------------------------------------
// Kernel 2: fused Gram + self-calibrating threshold filter, software-
// pipelined: MFMAs of tile t overlap consume of tile t-1 (double-buffered
// acc AND a-fragments). Diagonal handled in epilogue: self-sim (=1.0, always
// > tau) is the max candidate; the diag-containing block keeps top-11 and
// drops the max. Counts/taus written unconditionally -> no memset needed.
// ---------------------------------------------------------------------------
__global__ __launch_bounds__(256, 3) void kgram(const __bf16* __restrict__ an_all,
                                                float* __restrict__ tk,
                                                int* __restrict__ cnth,
                                                float* __restrict__ taug) {
  int dir = blockIdx.y;
  int rowg = blockIdx.x >> 1;
  int half = blockIdx.x & 1;
  const bf16x8* an8 = (const bf16x8*)(an_all + (size_t)dir * NB * ND);
  int w = threadIdx.x >> 6;
  int l = threadIdx.x & 63;
  int q = l >> 4;
  int c = l & 15;
  int row_base = rowg * 64;
  const int col0 = half * 4096;

  __shared__ float cand[64][CAP];
  __shared__ int lcnt[64];
  __shared__ float sred[2][4];
  if (threadIdx.x < 64) lcnt[threadIdx.x] = 0;

  // Row fragments (B-operand), resident all kernel (compiler -> AGPRs).
  bf16x8 brow[4][4];
#pragma unroll
  for (int rb = 0; rb < 4; ++rb)
#pragma unroll
    for (int kc = 0; kc < 4; ++kc)
      brow[rb][kc] = an8[(size_t)(row_base + rb * 16 + c) * 16 + kc * 4 + q];

  const bf16x8* pf0 = an8 + ((size_t)(col0 + w * 16 + c) * 16 + q);
  bf16x8 a[4], a2[4];
  const f32x4 zz = {0.f, 0.f, 0.f, 0.f};
  f32x4 accA[4], accB[4];

  auto loadA = [&](int t) {  // tile t -> a
    const bf16x8* p = pf0 + (size_t)(t & 63) * 1024;
#pragma unroll
    for (int kc = 0; kc < 4; ++kc) a[kc] = p[kc * 4];
  };
  auto loadA2 = [&](int t) {  // tile t -> a2
    const bf16x8* p = pf0 + (size_t)(t & 63) * 1024;
#pragma unroll
    for (int kc = 0; kc < 4; ++kc) a2[kc] = p[kc * 4];
  };
  auto mfma_tile = [&](f32x4* A, const bf16x8* src) {
#pragma unroll
    for (int rb = 0; rb < 4; ++rb)
      A[rb] = __builtin_amdgcn_mfma_f32_16x16x32_bf16(src[0], brow[rb][0], zz, 0, 0, 0);
#pragma unroll
    for (int kc = 1; kc < 4; ++kc)
#pragma unroll
      for (int rb = 0; rb < 4; ++rb)
        A[rb] = __builtin_amdgcn_mfma_f32_16x16x32_bf16(src[kc], brow[rb][kc], A[rb], 0, 0, 0);
  };

  // ---- tile 0: compute, stats (diag-masked), tau, consume ----
  loadA(0);
  mfma_tile(accA, a);
  loadA2(1);
  bool diag0 = (row_base == col0);
  int cq0 = col0 + w * 16 + q * 4;
  float s1 = 0.f, s2 = 0.f;
#pragma unroll
  for (int rb = 0; rb < 4; ++rb) {
    int myrow = row_base + rb * 16 + c;
#pragma unroll
    for (int r = 0; r < 4; ++r) {
      float v = accA[rb][r];
      v = (diag0 && (cq0 + r == myrow)) ? 0.f : v;
      s1 += v;
      s2 = fmaf(v, v, s2);
    }
  }
#pragma unroll
  for (int off = 1; off < 64; off <<= 1) {
    s1 += __shfl_xor(s1, off);
    s2 += __shfl_xor(s2, off);
  }
  if (l == 0) { sred[0][w] = s1; sred[1][w] = s2; }
  __syncthreads();
  float n = diag0 ? 4032.f : 4096.f;
  float ts1 = sred[0][0] + sred[0][1] + sred[0][2] + sred[0][3];
  float ts2 = sred[1][0] + sred[1][1] + sred[1][2] + sred[1][3];
  float mu = ts1 / n;
  float sig = sqrtf(fmaxf(ts2 / n - mu * mu, 0.f));
  float tau = mu + 2.5f * sig;  // lambda ~25 survivors per row-half
  if (threadIdx.x == 0) taug[(dir * 128 + rowg) * 2 + half] = tau;
  consume4(accA, cand, lcnt, tau, c);

  // ---- tile 1, then pipelined pairs (2,3),(4,5),...,(62,63) ----
  mfma_tile(accA, a2);
  loadA(2);
  for (int t = 2; t < 64; t += 2) {
    mfma_tile(accB, a);                 // tile t
    loadA2(t + 1);
    consume4(accA, cand, lcnt, tau, c); // tile t-1 (overlaps accB MFMAs)
    mfma_tile(accA, a2);                // tile t+1
    loadA(t + 2);                       // wraps harmlessly at t=62
    consume4(accB, cand, lcnt, tau, c); // tile t
  }
  consume4(accA, cand, lcnt, tau, c);   // tile 63

  // ---- epilogue: per-row top-11, drop max if this block holds the diag ----
  __syncthreads();
  if (threadIdx.x < 64) {
    int rl = threadIdx.x;
    int cc = lcnt[rl];
    float t11[11];
#pragma unroll
    for (int j = 0; j < 11; ++j) t11[j] = NEG_INF;
    int m = cc < CAP ? cc : CAP;
    for (int i = 0; i < m; ++i) {
      float v = cand[rl][i];
      if (v > t11[0]) insert11(t11, v);
    }
    bool diagq = (row_base >= col0) && (row_base < col0 + 4096);
    float* o = tk + ((size_t)(dir * NB + row_base + rl) * 2 + half) * 10;
    if (diagq) {  // t11[10] is the self-sim (max) -> drop it
#pragma unroll
      for (int j = 0; j < 10; ++j) o[j] = t11[j];
    } else {      // keep the 10 largest
#pragma unroll
      for (int j = 0; j < 10; ++j) o[j] = t11[j + 1];
    }
    cnth[(dir * NB + row_base + rl) * 2 + half] = cc;
  }
}

// ---------------------------------------------------------------------------
// Kernel 3: merge half-lists, tau-proof, soft-sort + BCE; exact brute-force
// fallback for unproven rows (statistically never fires).
// ---------------------------------------------------------------------------
__global__ __launch_bounds__(64, 1) void ksort(const float* __restrict__ tk,
                                               const float* __restrict__ pos,
                                               const int* __restrict__ cnth,
                                               const float* __restrict__ taug,
                                               const __bf16* __restrict__ an_all,
                                               float* __restrict__ out) {
  int tid = blockIdx.x * 64 + threadIdx.x;
  int dir = tid >> 13;
  int row = tid & (NB - 1);
  int lane = threadIdx.x;

  const float* A = tk + (size_t)(dir * NB + row) * 20;
  float s10[10];
#pragma unroll
  for (int j = 0; j < 10; ++j) s10[j] = A[j];
#pragma unroll
  for (int j = 0; j < 10; ++j) {
    float v = A[10 + j];
    if (v > s10[0]) insert10(s10, v);
  }
  int rowg = row >> 6;
  float tmax = fmaxf(taug[(dir * 128 + rowg) * 2], taug[(dir * 128 + rowg) * 2 + 1]);
  int2 cc2 = ((const int2*)cnth)[dir * NB + row];
  // Proof: every unreported sim is <= its half's tau <= tmax <= s10[0], and
  // no half overflowed CAP -> s10 is the exact top-10.
  bool ok = (cc2.x <= CAP) && (cc2.y <= CAP) && (s10[0] >= tmax);

  float C = 0.f;
  if (ok) {
    float x[11];
#pragma unroll
    for (int j = 0; j < 10; ++j) x[j] = s10[j];
    x[10] = pos[row];
    C = row_loss(x);
  }
#pragma unroll
  for (int off = 1; off < 64; off <<= 1) C += __shfl_xor(C, off);
  if (lane == 0) atomicAdd(out, C * (-1.f / (2.f * (float)NB * 11.f)));

  unsigned long long bad = __ballot(!ok);
  if (bad == 0ull) return;
  __shared__ float rv[128];
  __shared__ float lst[64][10];
  const __bf16* an = an_all + (size_t)dir * NB * ND;
  while (bad) {
    int b = __ffsll((long long)bad) - 1;
    bad &= bad - 1;
    int brow = (blockIdx.x * 64 + b) & (NB - 1);
    bf16x2 pr = ((const bf16x2*)an)[(size_t)brow * 64 + lane];
    rv[lane * 2] = (float)pr[0];
    rv[lane * 2 + 1] = (float)pr[1];
    __syncthreads();
    float t10[10];
#pragma unroll
    for (int j = 0; j < 10; ++j) t10[j] = NEG_INF;
    for (int i = 0; i < 128; ++i) {
      int col = lane + i * 64;
      if (col == brow) continue;
      const bf16x8* cp = (const bf16x8*)(an + (size_t)col * ND);
      float d = 0.f;
#pragma unroll
      for (int k = 0; k < 16; ++k) {
        bf16x8 p = cp[k];
#pragma unroll
        for (int e = 0; e < 8; ++e) d = fmaf(rv[k * 8 + e], (float)p[e], d);
      }
      if (d > t10[0]) insert10(t10, d);
    }
#pragma unroll
    for (int j = 0; j < 10; ++j) lst[lane][j] = t10[j];
    __syncthreads();
    if (lane == 0) {
      float cur[10];
#pragma unroll
      for (int j = 0; j < 10; ++j) cur[j] = lst[0][j];
      for (int s = 1; s < 64; ++s)
        for (int j = 0; j < 10; ++j) {
          float v = lst[s][j];
          if (v > cur[0]) insert10(cur, v);
        }
      float x[11];
#pragma unroll
      for (int j = 0; j < 10; ++j) x[j] = cur[j];
      x[10] = pos[brow];
      atomicAdd(out, row_loss(x) * (-1.f / (2.f * (float)NB * 11.f)));
    }
    __syncthreads();
  }
}

// ---------------------------------------------------------------------------
// ws: [an bf16 4MB][pos 32KB][tk 1.31MB][cnth 128KB][taug 2KB]. 3 nodes, no
// memsets: knorm zeroes d_out; cnth/taug written unconditionally by kgram.
// ---------------------------------------------------------------------------
extern "C" void kernel_launch(void* const* d_in, const int* in_sizes, int n_in,
                              void* d_out, int out_size, void* d_ws, size_t ws_size,
                              hipStream_t stream) {
  const float* aug1 = (const float*)d_in[0];
  const float* aug2 = (const float*)d_in[1];
  char* w = (char*)d_ws;
  __bf16* an = (__bf16*)w;
  float* pos = (float*)(w + (size_t)4 * 1024 * 1024);
  float* tk = pos + NB;
  int* cnth = (int*)(tk + (size_t)2 * NB * 20);
  float* taug = (float*)(cnth + 2 * NB * 2);

  knorm<<<dim3(NB / 4), dim3(256), 0, stream>>>(aug1, aug2, an, pos, (float*)d_out);
  kgram<<<dim3(256, 2), dim3(256), 0, stream>>>(an, tk, cnth, taug);
  ksort<<<dim3(2 * NB / 64), dim3(64), 0, stream>>>(tk, pos, cnth, taug, an, (float*)d_out);
}